// Round 2
// baseline (9520.119 us; speedup 1.0000x reference)
//
#include <hip/hip_runtime.h>
#include <hip/hip_bf16.h>
#include <math.h>

// EmotionModel forward, fp32 baseline (resubmit; rounds 0-1 were infra failures).
// Pipeline: fc GEMM -> VQ -> two 3-layer MLP projections (+LN) -> Q/K/V GEMMs
// -> per-frame 8-head attention (32 tokens, dh=128) -> out + vq_loss.
//
// Sizes: N_FR=2048 frames, SRC=1024, CTX=32, K_CB=64, H=8, DH=128.
// Workspace: 3 big buffers (256 MB each: xq, kvp, Kbuf) + 16 MB small ~= 784 MB.
// Guard: if ws_size is too small we return without launching (clean "incorrect"
// signal instead of an OOB GPU fault that kills the container).
// Q goes directly into d_out; attention runs in-place on it. V reuses xq.

#define N_FR 2048
#define SRCD 1024
#define KCB 64
#define CTXD 32
#define NHEAD 8
#define DHEAD 128

// ---------------------------------------------------------------------------
// Tiled SGEMM: C(M,N) = A(M,K) @ W(N,K)^T + bias, optional ReLU.
// 128x128 tile, BK=16, 256 threads, 8x8 per-thread microtile.
// All M,N,K here are multiples of 128/128/16 -> no bounds checks.
// ---------------------------------------------------------------------------
template<bool RELU>
__global__ __launch_bounds__(256)
void sgemm_xwt(const float* __restrict__ A, const float* __restrict__ W,
               const float* __restrict__ bias, float* __restrict__ C,
               int M, int N, int K) {
  constexpr int BM = 128, BN = 128, BK = 16;
  __shared__ float As[BK][BM];
  __shared__ float Bs[BK][BN];
  const int tid = threadIdx.x;
  const int tx = tid & 15;       // 0..15 -> n
  const int ty = tid >> 4;       // 0..15 -> m
  const int bm = blockIdx.x * BM;
  const int bn = blockIdx.y * BN;

  float acc[8][8];
#pragma unroll
  for (int i = 0; i < 8; i++)
#pragma unroll
    for (int j = 0; j < 8; j++) acc[i][j] = 0.f;

  const float* Abase = A + (size_t)bm * K;
  const float* Wbase = W + (size_t)bn * K;

  for (int kt = 0; kt < K; kt += BK) {
    __syncthreads();
    // load 128x16 A-tile and 128x16 W-tile, store k-major (transposed) in LDS
#pragma unroll
    for (int i = 0; i < 2; i++) {
      int s = tid + i * 256;            // 0..511
      int row = s >> 2;                 // 0..127
      int kq = (s & 3) * 4;             // 0,4,8,12
      float4 av = *(const float4*)&Abase[(size_t)row * K + kt + kq];
      As[kq + 0][row] = av.x; As[kq + 1][row] = av.y;
      As[kq + 2][row] = av.z; As[kq + 3][row] = av.w;
      float4 bv = *(const float4*)&Wbase[(size_t)row * K + kt + kq];
      Bs[kq + 0][row] = bv.x; Bs[kq + 1][row] = bv.y;
      Bs[kq + 2][row] = bv.z; Bs[kq + 3][row] = bv.w;
    }
    __syncthreads();
#pragma unroll
    for (int kk = 0; kk < BK; kk++) {
      const float4 a0 = *(const float4*)&As[kk][ty * 4];
      const float4 a1 = *(const float4*)&As[kk][64 + ty * 4];
      const float4 b0 = *(const float4*)&Bs[kk][tx * 4];
      const float4 b1 = *(const float4*)&Bs[kk][64 + tx * 4];
      const float ar[8] = {a0.x, a0.y, a0.z, a0.w, a1.x, a1.y, a1.z, a1.w};
      const float br[8] = {b0.x, b0.y, b0.z, b0.w, b1.x, b1.y, b1.z, b1.w};
#pragma unroll
      for (int i = 0; i < 8; i++)
#pragma unroll
        for (int j = 0; j < 8; j++) acc[i][j] += ar[i] * br[j];
    }
  }

  // epilogue: bias (+ReLU), float4 stores
  float bc0[4], bc1[4];
#pragma unroll
  for (int j = 0; j < 4; j++) {
    bc0[j] = bias[bn + tx * 4 + j];
    bc1[j] = bias[bn + 64 + tx * 4 + j];
  }
#pragma unroll
  for (int i = 0; i < 8; i++) {
    int m = bm + ((i < 4) ? (ty * 4 + i) : (64 + ty * 4 + (i - 4)));
    float v0[4], v1[4];
#pragma unroll
    for (int j = 0; j < 4; j++) {
      v0[j] = acc[i][j] + bc0[j];
      v1[j] = acc[i][4 + j] + bc1[j];
      if (RELU) { v0[j] = fmaxf(v0[j], 0.f); v1[j] = fmaxf(v1[j], 0.f); }
    }
    *(float4*)&C[(size_t)m * N + bn + tx * 4] =
        make_float4(v0[0], v0[1], v0[2], v0[3]);
    *(float4*)&C[(size_t)m * N + bn + 64 + tx * 4] =
        make_float4(v1[0], v1[1], v1[2], v1[3]);
  }
}

// ---------------------------------------------------------------------------
// codebook squared norms (64 rows of 1024)
// ---------------------------------------------------------------------------
__global__ __launch_bounds__(256)
void cbnorm_kernel(const float* __restrict__ cb, float* __restrict__ cbn) {
  int c = blockIdx.x, t = threadIdx.x;
  float4 v = *(const float4*)&cb[(size_t)c * SRCD + t * 4];
  float s = v.x * v.x + v.y * v.y + v.z * v.z + v.w * v.w;
  for (int o = 32; o; o >>= 1) s += __shfl_down(s, o);
  __shared__ float red[4];
  if ((t & 63) == 0) red[t >> 6] = s;
  __syncthreads();
  if (t == 0) cbn[c] = red[0] + red[1] + red[2] + red[3];
}

__global__ void zero_one(float* p) { p[0] = 0.f; }

// ---------------------------------------------------------------------------
// VQ: per row (2048 rows of 1024): dists to 64 codes, argmin (first-min),
// write quant row, accumulate sum((quant-z)^2) into loss.
// ---------------------------------------------------------------------------
__global__ __launch_bounds__(256)
void vq_kernel(const float* __restrict__ z, const float* __restrict__ cb,
               const float* __restrict__ cbn, float* __restrict__ quant,
               float* __restrict__ loss) {
  __shared__ float zrow[SRCD];
  __shared__ float dists[KCB];
  __shared__ int bi_s;
  __shared__ float red[4];
  const int r = blockIdx.x, t = threadIdx.x;

  *(float4*)&zrow[t * 4] = *(const float4*)&z[(size_t)r * SRCD + t * 4];
  __syncthreads();

  const int c = t >> 2, p = t & 3;          // code, k-quarter
  const float* crow = cb + (size_t)c * SRCD + p * 256;
  const float* zr = zrow + p * 256;
  float dot = 0.f;
  for (int k = 0; k < 256; k += 4) {
    float4 cv = *(const float4*)&crow[k];
    float4 zv = *(const float4*)&zr[k];
    dot += cv.x * zv.x + cv.y * zv.y + cv.z * zv.z + cv.w * zv.w;
  }
  dot += __shfl_xor(dot, 1);
  dot += __shfl_xor(dot, 2);
  if (p == 0) dists[c] = cbn[c] - 2.f * dot;   // ||z||^2 constant per row: dropped
  __syncthreads();
  if (t == 0) {
    float best = dists[0]; int bi = 0;
    for (int i = 1; i < KCB; i++)
      if (dists[i] < best) { best = dists[i]; bi = i; }
    bi_s = bi;
  }
  __syncthreads();
  const int bi = bi_s;
  float4 qv = *(const float4*)&cb[(size_t)bi * SRCD + t * 4];
  float4 zv = *(const float4*)&zrow[t * 4];
  float dx = qv.x - zv.x, dy = qv.y - zv.y, dz = qv.z - zv.z, dw = qv.w - zv.w;
  float l = dx * dx + dy * dy + dz * dz + dw * dw;
  *(float4*)&quant[(size_t)r * SRCD + t * 4] = qv;
  for (int o = 32; o; o >>= 1) l += __shfl_down(l, o);
  if ((t & 63) == 0) red[t >> 6] = l;
  __syncthreads();
  if (t == 0) atomicAdd(loss, red[0] + red[1] + red[2] + red[3]);
}

// ---------------------------------------------------------------------------
// LayerNorm in-place over rows of 1024 (one block per row)
// ---------------------------------------------------------------------------
__global__ __launch_bounds__(256)
void ln_inplace(float* __restrict__ X, const float* __restrict__ g,
                const float* __restrict__ b) {
  const size_t row = blockIdx.x;
  const int t = threadIdx.x;
  float* xp = X + row * SRCD;
  float4 v = *(const float4*)&xp[t * 4];
  __shared__ float red[4];

  float s = v.x + v.y + v.z + v.w;
  for (int o = 32; o; o >>= 1) s += __shfl_down(s, o);
  if ((t & 63) == 0) red[t >> 6] = s;
  __syncthreads();
  float mu = (red[0] + red[1] + red[2] + red[3]) * (1.f / 1024.f);
  __syncthreads();

  float dx = v.x - mu, dy = v.y - mu, dz = v.z - mu, dw = v.w - mu;
  float ss = dx * dx + dy * dy + dz * dz + dw * dw;
  for (int o = 32; o; o >>= 1) ss += __shfl_down(ss, o);
  if ((t & 63) == 0) red[t >> 6] = ss;
  __syncthreads();
  float var = (red[0] + red[1] + red[2] + red[3]) * (1.f / 1024.f);
  float rs = rsqrtf(var + 1e-5f);

  float4 gv = *(const float4*)&g[t * 4];
  float4 bv = *(const float4*)&b[t * 4];
  float4 o4 = make_float4(dx * rs * gv.x + bv.x, dy * rs * gv.y + bv.y,
                          dz * rs * gv.z + bv.z, dw * rs * gv.w + bv.w);
  *(float4*)&xp[t * 4] = o4;
}

// ---------------------------------------------------------------------------
// Attention per (frame, head): 32x128 Q,K,V tiles; in-place on QO.
// ---------------------------------------------------------------------------
__global__ __launch_bounds__(256)
void attn_kernel(float* __restrict__ QO, const float* __restrict__ Kb,
                 const float* __restrict__ Vb) {
  __shared__ float Qs[CTXD][132], Ks[CTXD][132], Vs[CTXD][132];
  __shared__ float Ps[CTXD][33];
  const int f = blockIdx.x, h = blockIdx.y;
  const int t = threadIdx.x;
  const size_t base = (size_t)f * CTXD * SRCD + (size_t)h * DHEAD;

#pragma unroll
  for (int i = 0; i < 4; i++) {
    int s = t + i * 256;                 // 0..1023
    int q = s >> 5, dq = (s & 31) * 4;   // row, float4 col
    size_t ga = base + (size_t)q * SRCD + dq;
    *(float4*)&Qs[q][dq] = *(const float4*)&QO[ga];
    *(float4*)&Ks[q][dq] = *(const float4*)&Kb[ga];
    *(float4*)&Vs[q][dq] = *(const float4*)&Vb[ga];
  }
  __syncthreads();

  // scores: thread -> (q = t/8, 4 k's)
  const int q = t >> 3, kb4 = (t & 7) * 4;
  float sc0 = 0.f, sc1 = 0.f, sc2 = 0.f, sc3 = 0.f;
  for (int kk = 0; kk < DHEAD; kk++) {
    float qv = Qs[q][kk];
    sc0 += qv * Ks[kb4 + 0][kk];
    sc1 += qv * Ks[kb4 + 1][kk];
    sc2 += qv * Ks[kb4 + 2][kk];
    sc3 += qv * Ks[kb4 + 3][kk];
  }
  const float scale = 0.08838834764831845f;   // 1/sqrt(128)
  sc0 *= scale; sc1 *= scale; sc2 *= scale; sc3 *= scale;
  float m = fmaxf(fmaxf(sc0, sc1), fmaxf(sc2, sc3));
  for (int o = 1; o < 8; o <<= 1) m = fmaxf(m, __shfl_xor(m, o));
  float e0 = expf(sc0 - m), e1 = expf(sc1 - m), e2 = expf(sc2 - m), e3 = expf(sc3 - m);
  float s = e0 + e1 + e2 + e3;
  for (int o = 1; o < 8; o <<= 1) s += __shfl_xor(s, o);
  float inv = 1.f / s;
  Ps[q][kb4 + 0] = e0 * inv; Ps[q][kb4 + 1] = e1 * inv;
  Ps[q][kb4 + 2] = e2 * inv; Ps[q][kb4 + 3] = e3 * inv;
  __syncthreads();

  // PV: thread -> (q = t/8, d in {4*(t%8) + 32s + j})
  const int d4 = (t & 7) * 4, qq = t >> 3;
  float accv[4][4];
#pragma unroll
  for (int a = 0; a < 4; a++)
#pragma unroll
    for (int j = 0; j < 4; j++) accv[a][j] = 0.f;
  for (int k = 0; k < CTXD; k++) {
    float p = Ps[qq][k];
#pragma unroll
    for (int sg = 0; sg < 4; sg++) {
      int d = d4 + sg * 32;
      accv[sg][0] += p * Vs[k][d + 0];
      accv[sg][1] += p * Vs[k][d + 1];
      accv[sg][2] += p * Vs[k][d + 2];
      accv[sg][3] += p * Vs[k][d + 3];
    }
  }
  const size_t ob = base + (size_t)qq * SRCD;
#pragma unroll
  for (int sg = 0; sg < 4; sg++) {
    *(float4*)&QO[ob + d4 + sg * 32] =
        make_float4(accv[sg][0], accv[sg][1], accv[sg][2], accv[sg][3]);
  }
}

__global__ void finalize_loss(const float* __restrict__ loss, float* __restrict__ out) {
  float L = loss[0] * (1.f / 2097152.f);     // mean over 2048*1024 elems
  out[67108864] = L + 0.25f * L;             // q_loss + COMMIT*e_loss
}

// ---------------------------------------------------------------------------
extern "C" void kernel_launch(void* const* d_in, const int* in_sizes, int n_in,
                              void* d_out, int out_size, void* d_ws, size_t ws_size,
                              hipStream_t stream) {
  const float* emo  = (const float*)d_in[0];   // (2048, 256)
  const float* fc_w = (const float*)d_in[1];   // (1024, 256)
  const float* fc_b = (const float*)d_in[2];
  const float* cb   = (const float*)d_in[3];   // (64, 1024)
  const float* ew1  = (const float*)d_in[4];   // (1024, 256)
  const float* eb1  = (const float*)d_in[5];
  const float* ew2  = (const float*)d_in[6];   // (1024, 1024)
  const float* eb2  = (const float*)d_in[7];
  const float* ew3  = (const float*)d_in[8];   // (32768, 1024)
  const float* eb3  = (const float*)d_in[9];
  const float* elng = (const float*)d_in[10];
  const float* elnb = (const float*)d_in[11];
  const float* kw1  = (const float*)d_in[12];  // (1024, 1024)
  const float* kb1  = (const float*)d_in[13];
  const float* kw2  = (const float*)d_in[14];
  const float* kb2  = (const float*)d_in[15];
  const float* kw3  = (const float*)d_in[16];  // (32768, 1024)
  const float* kb3  = (const float*)d_in[17];
  const float* klng = (const float*)d_in[18];
  const float* klnb = (const float*)d_in[19];
  const float* qw   = (const float*)d_in[20];
  const float* qb   = (const float*)d_in[21];
  const float* kw   = (const float*)d_in[22];
  const float* kbv  = (const float*)d_in[23];
  const float* vw   = (const float*)d_in[24];
  const float* vb   = (const float*)d_in[25];
  float* out = (float*)d_out;

  const size_t NZ   = (size_t)N_FR * SRCD;          // 2,097,152
  const size_t NBIG = (size_t)N_FR * CTXD * SRCD;   // 67,108,864

  // Workspace budget guard: 2 small (quant, h2) + h1-aliased-z + 3 big + 128.
  const size_t need = (3 * NZ + 3 * NBIG + 128) * sizeof(float);
  if (ws_size < need) return;   // clean failure signal, not an OOB GPU fault

  float* ws    = (float*)d_ws;
  float* z     = ws;            // also reused as h1 (z dead after vq_kernel)
  float* quant = z + NZ;
  float* h2    = quant + NZ;
  float* h1    = z;             // alias: stream order makes this safe
  float* xq    = h2 + NZ;       // later reused as V
  float* kvp   = xq + NBIG;
  float* Kbuf  = kvp + NBIG;
  float* cbn   = Kbuf + NBIG;
  float* lossw = cbn + 64;

  dim3 blk(256);
  dim3 gSmallK(N_FR / 128, SRCD / 128);    // (16, 8)
  dim3 gBig(N_FR / 128, 32768 / 128);      // (16, 256)
  dim3 gQKV(65536 / 128, SRCD / 128);      // (512, 8)

  zero_one<<<1, 1, 0, stream>>>(lossw);
  cbnorm_kernel<<<KCB, blk, 0, stream>>>(cb, cbn);

  // z = emo @ fc_w^T + fc_b
  sgemm_xwt<false><<<gSmallK, blk, 0, stream>>>(emo, fc_w, fc_b, z, N_FR, SRCD, 256);
  vq_kernel<<<N_FR, blk, 0, stream>>>(z, cb, cbn, quant, lossw);

  // xq path (input = emo_prompts); h1 aliases z (z consumed by vq above)
  sgemm_xwt<true ><<<gSmallK, blk, 0, stream>>>(emo, ew1, eb1, h1, N_FR, SRCD, 256);
  sgemm_xwt<true ><<<gSmallK, blk, 0, stream>>>(h1, ew2, eb2, h2, N_FR, SRCD, 1024);
  sgemm_xwt<false><<<gBig,    blk, 0, stream>>>(h2, ew3, eb3, xq, N_FR, 32768, 1024);
  ln_inplace<<<N_FR * CTXD, blk, 0, stream>>>(xq, elng, elnb);

  // kv path (input = quant == straight-through emo_retrieval)
  sgemm_xwt<true ><<<gSmallK, blk, 0, stream>>>(quant, kw1, kb1, h1, N_FR, SRCD, 1024);
  sgemm_xwt<true ><<<gSmallK, blk, 0, stream>>>(h1, kw2, kb2, h2, N_FR, SRCD, 1024);
  sgemm_xwt<false><<<gBig,    blk, 0, stream>>>(h2, kw3, kb3, kvp, N_FR, 32768, 1024);
  ln_inplace<<<N_FR * CTXD, blk, 0, stream>>>(kvp, klng, klnb);

  // Q -> d_out, K -> Kbuf, V -> xq (xq dead after Q)
  sgemm_xwt<false><<<gQKV, blk, 0, stream>>>(xq,  qw, qb,  out,  65536, SRCD, 1024);
  sgemm_xwt<false><<<gQKV, blk, 0, stream>>>(kvp, kw, kbv, Kbuf, 65536, SRCD, 1024);
  sgemm_xwt<false><<<gQKV, blk, 0, stream>>>(kvp, vw, vb,  xq,   65536, SRCD, 1024);

  // attention in-place on d_out (Q region), per (frame, head)
  attn_kernel<<<dim3(N_FR, NHEAD), blk, 0, stream>>>(out, Kbuf, xq);

  finalize_loss<<<1, 1, 0, stream>>>(lossw, out);
}

// Round 3
// 4064.820 us; speedup vs baseline: 2.3421x; 2.3421x over previous
//
#include <hip/hip_runtime.h>
#include <hip/hip_bf16.h>
#include <math.h>

// EmotionModel forward. Round 3: the five big GEMMs (2x w3, Q/K/V) move to
// split-bf16 (bf16x3 / Ootomo) MFMA: A = Ah+Al, W = Wh+Wl in bf16,
// C ~= Ah*Wh + Ah*Wl + Al*Wh with fp32 MFMA accumulation (~1e-5 rel error).
// Conversion fused in-kernel (reg-stage fp32 -> split -> LDS), so the
// workspace layout is IDENTICAL to the proven round-2 footprint (784 MB).
// Small GEMMs (fc,w1,w2), VQ, LN, attention unchanged (proven fp32 path).

#define N_FR 2048
#define SRCD 1024
#define KCB 64
#define CTXD 32
#define NHEAD 8
#define DHEAD 128

typedef __attribute__((ext_vector_type(8))) short bf16x8;
typedef __attribute__((ext_vector_type(4))) float f32x4;
typedef __attribute__((ext_vector_type(4))) unsigned short u16x4;

__device__ __forceinline__ unsigned short bf16rne(float x) {
  unsigned u = __float_as_uint(x);
  return (unsigned short)((u + 0x7FFFu + ((u >> 16) & 1u)) >> 16);
}

// ---------------------------------------------------------------------------
// Split-bf16 MFMA GEMM: C(M,N) = A(M,K) @ W(N,K)^T + bias.
// 128x128 tile, BK=32, 256 threads (4 waves, 2x2 wave grid, 64x64 per wave).
// LDS planes padded to 40 ushorts (80B) per row -> frag ds_read_b128 is
// bank-uniform (rows 0-7 cover all 32 banks at stride 80B).
// K-step: [convert regs][bar][ds_write hi/lo][bar][prefetch next][frags+48 MFMA]
// ---------------------------------------------------------------------------
__global__ __launch_bounds__(256, 2)
void gemm3_xwt(const float* __restrict__ A, const float* __restrict__ W,
               const float* __restrict__ bias, float* __restrict__ C,
               int N, int K, int m_on_x) {
  __shared__ unsigned short Ah[128][40], Al[128][40], Wh[128][40], Wl[128][40];
  const int t = threadIdx.x;
  const int bm = (m_on_x ? blockIdx.x : blockIdx.y) * 128;
  const int bn = (m_on_x ? blockIdx.y : blockIdx.x) * 128;

  const int lane = t & 63;
  const int wid = t >> 6;
  const int wr = (wid >> 1) * 64;     // wave row offset in tile
  const int wc = (wid & 1) * 64;      // wave col offset in tile
  const int fr = lane & 15;           // fragment row/col
  const int kg = lane >> 4;           // k-group (8 bf16 each)

  // staging map: linear float4 index s = t + i*256 -> row = (t>>3)+32i, c4 = t&7
  const int r0 = t >> 3, c4 = t & 7;
  const float* Abase = A + (size_t)(bm + r0) * K + c4 * 4;
  const float* Wbase = W + (size_t)(bn + r0) * K + c4 * 4;

  f32x4 acc[4][4];
#pragma unroll
  for (int i = 0; i < 4; i++)
#pragma unroll
    for (int j = 0; j < 4; j++) acc[i][j] = (f32x4){0.f, 0.f, 0.f, 0.f};

  float4 av[4], wv[4];
#pragma unroll
  for (int i = 0; i < 4; i++) {
    av[i] = *(const float4*)&Abase[(size_t)i * 32 * K];
    wv[i] = *(const float4*)&Wbase[(size_t)i * 32 * K];
  }

  for (int kt = 0; kt < K; kt += 32) {
    // ---- convert current tiles (regs) to hi/lo bf16 ----
    u16x4 ahv[4], alv[4], whv[4], wlv[4];
#pragma unroll
    for (int i = 0; i < 4; i++) {
      const float a4[4] = {av[i].x, av[i].y, av[i].z, av[i].w};
      const float w4[4] = {wv[i].x, wv[i].y, wv[i].z, wv[i].w};
#pragma unroll
      for (int j = 0; j < 4; j++) {
        unsigned short h = bf16rne(a4[j]);
        ahv[i][j] = h;
        alv[i][j] = bf16rne(a4[j] - __uint_as_float((unsigned)h << 16));
        unsigned short g = bf16rne(w4[j]);
        whv[i][j] = g;
        wlv[i][j] = bf16rne(w4[j] - __uint_as_float((unsigned)g << 16));
      }
    }
    __syncthreads();   // previous compute done reading LDS
#pragma unroll
    for (int i = 0; i < 4; i++) {
      int row = r0 + i * 32;
      *(u16x4*)&Ah[row][c4 * 4] = ahv[i];
      *(u16x4*)&Al[row][c4 * 4] = alv[i];
      *(u16x4*)&Wh[row][c4 * 4] = whv[i];
      *(u16x4*)&Wl[row][c4 * 4] = wlv[i];
    }
    __syncthreads();

    // ---- prefetch next K-step (latency hides under MFMAs) ----
    if (kt + 32 < K) {
#pragma unroll
      for (int i = 0; i < 4; i++) {
        av[i] = *(const float4*)&Abase[(size_t)i * 32 * K + kt + 32];
        wv[i] = *(const float4*)&Wbase[(size_t)i * 32 * K + kt + 32];
      }
    }

    // ---- fragments + 48 MFMAs ----
    bf16x8 af_h[4], af_l[4], bf_h[4], bf_l[4];
#pragma unroll
    for (int mf = 0; mf < 4; mf++) {
      int r = wr + mf * 16 + fr;
      af_h[mf] = *(const bf16x8*)&Ah[r][kg * 8];
      af_l[mf] = *(const bf16x8*)&Al[r][kg * 8];
    }
#pragma unroll
    for (int nf = 0; nf < 4; nf++) {
      int r = wc + nf * 16 + fr;
      bf_h[nf] = *(const bf16x8*)&Wh[r][kg * 8];
      bf_l[nf] = *(const bf16x8*)&Wl[r][kg * 8];
    }
#pragma unroll
    for (int mf = 0; mf < 4; mf++)
#pragma unroll
      for (int nf = 0; nf < 4; nf++) {
        acc[mf][nf] = __builtin_amdgcn_mfma_f32_16x16x32_bf16(
            af_h[mf], bf_h[nf], acc[mf][nf], 0, 0, 0);
        acc[mf][nf] = __builtin_amdgcn_mfma_f32_16x16x32_bf16(
            af_h[mf], bf_l[nf], acc[mf][nf], 0, 0, 0);
        acc[mf][nf] = __builtin_amdgcn_mfma_f32_16x16x32_bf16(
            af_l[mf], bf_h[nf], acc[mf][nf], 0, 0, 0);
      }
  }

  // ---- epilogue: C/D layout col=lane&15, row=(lane>>4)*4+reg [verified] ----
  const int col = lane & 15, rq = (lane >> 4) * 4;
#pragma unroll
  for (int mf = 0; mf < 4; mf++) {
    int mbase = bm + wr + mf * 16 + rq;
#pragma unroll
    for (int nf = 0; nf < 4; nf++) {
      int n = bn + wc + nf * 16 + col;
      float bv = bias[n];
#pragma unroll
      for (int r = 0; r < 4; r++)
        C[(size_t)(mbase + r) * N + n] = acc[mf][nf][r] + bv;
    }
  }
}

// ---------------------------------------------------------------------------
// Tiled SGEMM (fp32) for the small GEMMs: fc, w1, w2.
// ---------------------------------------------------------------------------
template<bool RELU>
__global__ __launch_bounds__(256)
void sgemm_xwt(const float* __restrict__ A, const float* __restrict__ W,
               const float* __restrict__ bias, float* __restrict__ C,
               int M, int N, int K) {
  constexpr int BM = 128, BN = 128, BK = 16;
  __shared__ float As[BK][BM];
  __shared__ float Bs[BK][BN];
  const int tid = threadIdx.x;
  const int tx = tid & 15;
  const int ty = tid >> 4;
  const int bm = blockIdx.x * BM;
  const int bn = blockIdx.y * BN;

  float acc[8][8];
#pragma unroll
  for (int i = 0; i < 8; i++)
#pragma unroll
    for (int j = 0; j < 8; j++) acc[i][j] = 0.f;

  const float* Abase = A + (size_t)bm * K;
  const float* Wbase = W + (size_t)bn * K;

  for (int kt = 0; kt < K; kt += BK) {
    __syncthreads();
#pragma unroll
    for (int i = 0; i < 2; i++) {
      int s = tid + i * 256;
      int row = s >> 2;
      int kq = (s & 3) * 4;
      float4 av = *(const float4*)&Abase[(size_t)row * K + kt + kq];
      As[kq + 0][row] = av.x; As[kq + 1][row] = av.y;
      As[kq + 2][row] = av.z; As[kq + 3][row] = av.w;
      float4 bv = *(const float4*)&Wbase[(size_t)row * K + kt + kq];
      Bs[kq + 0][row] = bv.x; Bs[kq + 1][row] = bv.y;
      Bs[kq + 2][row] = bv.z; Bs[kq + 3][row] = bv.w;
    }
    __syncthreads();
#pragma unroll
    for (int kk = 0; kk < BK; kk++) {
      const float4 a0 = *(const float4*)&As[kk][ty * 4];
      const float4 a1 = *(const float4*)&As[kk][64 + ty * 4];
      const float4 b0 = *(const float4*)&Bs[kk][tx * 4];
      const float4 b1 = *(const float4*)&Bs[kk][64 + tx * 4];
      const float ar[8] = {a0.x, a0.y, a0.z, a0.w, a1.x, a1.y, a1.z, a1.w};
      const float br[8] = {b0.x, b0.y, b0.z, b0.w, b1.x, b1.y, b1.z, b1.w};
#pragma unroll
      for (int i = 0; i < 8; i++)
#pragma unroll
        for (int j = 0; j < 8; j++) acc[i][j] += ar[i] * br[j];
    }
  }

  float bc0[4], bc1[4];
#pragma unroll
  for (int j = 0; j < 4; j++) {
    bc0[j] = bias[bn + tx * 4 + j];
    bc1[j] = bias[bn + 64 + tx * 4 + j];
  }
#pragma unroll
  for (int i = 0; i < 8; i++) {
    int m = bm + ((i < 4) ? (ty * 4 + i) : (64 + ty * 4 + (i - 4)));
    float v0[4], v1[4];
#pragma unroll
    for (int j = 0; j < 4; j++) {
      v0[j] = acc[i][j] + bc0[j];
      v1[j] = acc[i][4 + j] + bc1[j];
      if (RELU) { v0[j] = fmaxf(v0[j], 0.f); v1[j] = fmaxf(v1[j], 0.f); }
    }
    *(float4*)&C[(size_t)m * N + bn + tx * 4] =
        make_float4(v0[0], v0[1], v0[2], v0[3]);
    *(float4*)&C[(size_t)m * N + bn + 64 + tx * 4] =
        make_float4(v1[0], v1[1], v1[2], v1[3]);
  }
}

// ---------------------------------------------------------------------------
__global__ __launch_bounds__(256)
void cbnorm_kernel(const float* __restrict__ cb, float* __restrict__ cbn) {
  int c = blockIdx.x, t = threadIdx.x;
  float4 v = *(const float4*)&cb[(size_t)c * SRCD + t * 4];
  float s = v.x * v.x + v.y * v.y + v.z * v.z + v.w * v.w;
  for (int o = 32; o; o >>= 1) s += __shfl_down(s, o);
  __shared__ float red[4];
  if ((t & 63) == 0) red[t >> 6] = s;
  __syncthreads();
  if (t == 0) cbn[c] = red[0] + red[1] + red[2] + red[3];
}

__global__ void zero_one(float* p) { p[0] = 0.f; }

__global__ __launch_bounds__(256)
void vq_kernel(const float* __restrict__ z, const float* __restrict__ cb,
               const float* __restrict__ cbn, float* __restrict__ quant,
               float* __restrict__ loss) {
  __shared__ float zrow[SRCD];
  __shared__ float dists[KCB];
  __shared__ int bi_s;
  __shared__ float red[4];
  const int r = blockIdx.x, t = threadIdx.x;

  *(float4*)&zrow[t * 4] = *(const float4*)&z[(size_t)r * SRCD + t * 4];
  __syncthreads();

  const int c = t >> 2, p = t & 3;
  const float* crow = cb + (size_t)c * SRCD + p * 256;
  const float* zr = zrow + p * 256;
  float dot = 0.f;
  for (int k = 0; k < 256; k += 4) {
    float4 cv = *(const float4*)&crow[k];
    float4 zv = *(const float4*)&zr[k];
    dot += cv.x * zv.x + cv.y * zv.y + cv.z * zv.z + cv.w * zv.w;
  }
  dot += __shfl_xor(dot, 1);
  dot += __shfl_xor(dot, 2);
  if (p == 0) dists[c] = cbn[c] - 2.f * dot;
  __syncthreads();
  if (t == 0) {
    float best = dists[0]; int bi = 0;
    for (int i = 1; i < KCB; i++)
      if (dists[i] < best) { best = dists[i]; bi = i; }
    bi_s = bi;
  }
  __syncthreads();
  const int bi = bi_s;
  float4 qv = *(const float4*)&cb[(size_t)bi * SRCD + t * 4];
  float4 zv = *(const float4*)&zrow[t * 4];
  float dx = qv.x - zv.x, dy = qv.y - zv.y, dz = qv.z - zv.z, dw = qv.w - zv.w;
  float l = dx * dx + dy * dy + dz * dz + dw * dw;
  *(float4*)&quant[(size_t)r * SRCD + t * 4] = qv;
  for (int o = 32; o; o >>= 1) l += __shfl_down(l, o);
  if ((t & 63) == 0) red[t >> 6] = l;
  __syncthreads();
  if (t == 0) atomicAdd(loss, red[0] + red[1] + red[2] + red[3]);
}

__global__ __launch_bounds__(256)
void ln_inplace(float* __restrict__ X, const float* __restrict__ g,
                const float* __restrict__ b) {
  const size_t row = blockIdx.x;
  const int t = threadIdx.x;
  float* xp = X + row * SRCD;
  float4 v = *(const float4*)&xp[t * 4];
  __shared__ float red[4];

  float s = v.x + v.y + v.z + v.w;
  for (int o = 32; o; o >>= 1) s += __shfl_down(s, o);
  if ((t & 63) == 0) red[t >> 6] = s;
  __syncthreads();
  float mu = (red[0] + red[1] + red[2] + red[3]) * (1.f / 1024.f);
  __syncthreads();

  float dx = v.x - mu, dy = v.y - mu, dz = v.z - mu, dw = v.w - mu;
  float ss = dx * dx + dy * dy + dz * dz + dw * dw;
  for (int o = 32; o; o >>= 1) ss += __shfl_down(ss, o);
  if ((t & 63) == 0) red[t >> 6] = ss;
  __syncthreads();
  float var = (red[0] + red[1] + red[2] + red[3]) * (1.f / 1024.f);
  float rs = rsqrtf(var + 1e-5f);

  float4 gv = *(const float4*)&g[t * 4];
  float4 bv = *(const float4*)&b[t * 4];
  float4 o4 = make_float4(dx * rs * gv.x + bv.x, dy * rs * gv.y + bv.y,
                          dz * rs * gv.z + bv.z, dw * rs * gv.w + bv.w);
  *(float4*)&xp[t * 4] = o4;
}

__global__ __launch_bounds__(256)
void attn_kernel(float* __restrict__ QO, const float* __restrict__ Kb,
                 const float* __restrict__ Vb) {
  __shared__ float Qs[CTXD][132], Ks[CTXD][132], Vs[CTXD][132];
  __shared__ float Ps[CTXD][33];
  const int f = blockIdx.x, h = blockIdx.y;
  const int t = threadIdx.x;
  const size_t base = (size_t)f * CTXD * SRCD + (size_t)h * DHEAD;

#pragma unroll
  for (int i = 0; i < 4; i++) {
    int s = t + i * 256;
    int q = s >> 5, dq = (s & 31) * 4;
    size_t ga = base + (size_t)q * SRCD + dq;
    *(float4*)&Qs[q][dq] = *(const float4*)&QO[ga];
    *(float4*)&Ks[q][dq] = *(const float4*)&Kb[ga];
    *(float4*)&Vs[q][dq] = *(const float4*)&Vb[ga];
  }
  __syncthreads();

  const int q = t >> 3, kb4 = (t & 7) * 4;
  float sc0 = 0.f, sc1 = 0.f, sc2 = 0.f, sc3 = 0.f;
  for (int kk = 0; kk < DHEAD; kk++) {
    float qv = Qs[q][kk];
    sc0 += qv * Ks[kb4 + 0][kk];
    sc1 += qv * Ks[kb4 + 1][kk];
    sc2 += qv * Ks[kb4 + 2][kk];
    sc3 += qv * Ks[kb4 + 3][kk];
  }
  const float scale = 0.08838834764831845f;
  sc0 *= scale; sc1 *= scale; sc2 *= scale; sc3 *= scale;
  float m = fmaxf(fmaxf(sc0, sc1), fmaxf(sc2, sc3));
  for (int o = 1; o < 8; o <<= 1) m = fmaxf(m, __shfl_xor(m, o));
  float e0 = expf(sc0 - m), e1 = expf(sc1 - m), e2 = expf(sc2 - m), e3 = expf(sc3 - m);
  float s = e0 + e1 + e2 + e3;
  for (int o = 1; o < 8; o <<= 1) s += __shfl_xor(s, o);
  float inv = 1.f / s;
  Ps[q][kb4 + 0] = e0 * inv; Ps[q][kb4 + 1] = e1 * inv;
  Ps[q][kb4 + 2] = e2 * inv; Ps[q][kb4 + 3] = e3 * inv;
  __syncthreads();

  const int d4 = (t & 7) * 4, qq = t >> 3;
  float accv[4][4];
#pragma unroll
  for (int a = 0; a < 4; a++)
#pragma unroll
    for (int j = 0; j < 4; j++) accv[a][j] = 0.f;
  for (int k = 0; k < CTXD; k++) {
    float p = Ps[qq][k];
#pragma unroll
    for (int sg = 0; sg < 4; sg++) {
      int d = d4 + sg * 32;
      accv[sg][0] += p * Vs[k][d + 0];
      accv[sg][1] += p * Vs[k][d + 1];
      accv[sg][2] += p * Vs[k][d + 2];
      accv[sg][3] += p * Vs[k][d + 3];
    }
  }
  const size_t ob = base + (size_t)qq * SRCD;
#pragma unroll
  for (int sg = 0; sg < 4; sg++) {
    *(float4*)&QO[ob + d4 + sg * 32] =
        make_float4(accv[sg][0], accv[sg][1], accv[sg][2], accv[sg][3]);
  }
}

__global__ void finalize_loss(const float* __restrict__ loss, float* __restrict__ out) {
  float L = loss[0] * (1.f / 2097152.f);
  out[67108864] = L + 0.25f * L;
}

// ---------------------------------------------------------------------------
extern "C" void kernel_launch(void* const* d_in, const int* in_sizes, int n_in,
                              void* d_out, int out_size, void* d_ws, size_t ws_size,
                              hipStream_t stream) {
  const float* emo  = (const float*)d_in[0];
  const float* fc_w = (const float*)d_in[1];
  const float* fc_b = (const float*)d_in[2];
  const float* cb   = (const float*)d_in[3];
  const float* ew1  = (const float*)d_in[4];
  const float* eb1  = (const float*)d_in[5];
  const float* ew2  = (const float*)d_in[6];
  const float* eb2  = (const float*)d_in[7];
  const float* ew3  = (const float*)d_in[8];
  const float* eb3  = (const float*)d_in[9];
  const float* elng = (const float*)d_in[10];
  const float* elnb = (const float*)d_in[11];
  const float* kw1  = (const float*)d_in[12];
  const float* kb1  = (const float*)d_in[13];
  const float* kw2  = (const float*)d_in[14];
  const float* kb2  = (const float*)d_in[15];
  const float* kw3  = (const float*)d_in[16];
  const float* kb3  = (const float*)d_in[17];
  const float* klng = (const float*)d_in[18];
  const float* klnb = (const float*)d_in[19];
  const float* qw   = (const float*)d_in[20];
  const float* qb   = (const float*)d_in[21];
  const float* kw   = (const float*)d_in[22];
  const float* kbv  = (const float*)d_in[23];
  const float* vw   = (const float*)d_in[24];
  const float* vb   = (const float*)d_in[25];
  float* out = (float*)d_out;

  const size_t NZ   = (size_t)N_FR * SRCD;
  const size_t NBIG = (size_t)N_FR * CTXD * SRCD;

  const size_t need = (3 * NZ + 3 * NBIG + 128) * sizeof(float);
  if (ws_size < need) return;

  float* ws    = (float*)d_ws;
  float* z     = ws;            // reused as h1 after VQ consumes z
  float* quant = z + NZ;
  float* h2    = quant + NZ;
  float* h1    = z;
  float* xq    = h2 + NZ;       // later reused as V
  float* kvp   = xq + NBIG;
  float* Kbuf  = kvp + NBIG;
  float* cbn   = Kbuf + NBIG;
  float* lossw = cbn + 64;

  dim3 blk(256);
  dim3 gSmallK(N_FR / 128, SRCD / 128);     // (16, 8)
  dim3 gW3(16, 256);                        // m_on_x=1: x=M/128, y=N/128
  dim3 gQKV(8, 512);                        // m_on_x=0: x=N/128, y=M/128

  zero_one<<<1, 1, 0, stream>>>(lossw);
  cbnorm_kernel<<<KCB, blk, 0, stream>>>(cb, cbn);

  sgemm_xwt<false><<<gSmallK, blk, 0, stream>>>(emo, fc_w, fc_b, z, N_FR, SRCD, 256);
  vq_kernel<<<N_FR, blk, 0, stream>>>(z, cb, cbn, quant, lossw);

  // xq path
  sgemm_xwt<true ><<<gSmallK, blk, 0, stream>>>(emo, ew1, eb1, h1, N_FR, SRCD, 256);
  sgemm_xwt<true ><<<gSmallK, blk, 0, stream>>>(h1, ew2, eb2, h2, N_FR, SRCD, 1024);
  gemm3_xwt<<<gW3, blk, 0, stream>>>(h2, ew3, eb3, xq, 32768, 1024, 1);
  ln_inplace<<<N_FR * CTXD, blk, 0, stream>>>(xq, elng, elnb);

  // kv path
  sgemm_xwt<true ><<<gSmallK, blk, 0, stream>>>(quant, kw1, kb1, h1, N_FR, SRCD, 1024);
  sgemm_xwt<true ><<<gSmallK, blk, 0, stream>>>(h1, kw2, kb2, h2, N_FR, SRCD, 1024);
  gemm3_xwt<<<gW3, blk, 0, stream>>>(h2, kw3, kb3, kvp, 32768, 1024, 1);
  ln_inplace<<<N_FR * CTXD, blk, 0, stream>>>(kvp, klng, klnb);

  // Q -> d_out, K -> Kbuf, V -> xq (xq dead after Q GEMM)
  gemm3_xwt<<<gQKV, blk, 0, stream>>>(xq,  qw, qb,  out,  1024, 1024, 0);
  gemm3_xwt<<<gQKV, blk, 0, stream>>>(kvp, kw, kbv, Kbuf, 1024, 1024, 0);
  gemm3_xwt<<<gQKV, blk, 0, stream>>>(kvp, vw, vb,  xq,   1024, 1024, 0);

  attn_kernel<<<dim3(N_FR, NHEAD), blk, 0, stream>>>(out, Kbuf, xq);

  finalize_loss<<<1, 1, 0, stream>>>(lossw, out);
}